// Round 9
// baseline (344.010 us; speedup 1.0000x reference)
//
#include <hip/hip_runtime.h>
#include <math.h>

#define B_ 8
#define N_ 16384
#define G_ 128      // NUM_GROUPS
#define GS_ 32      // GROUP_SIZE
#define UK_ 128     // UPSCALE_K
#define FPS_T 512
#define FPS_W 8     // waves per FPS block
#define FPS_BLK 4   // blocks (slices) per batch, stride-8 blockIdx => same XCD
#define SLICE (N_ / FPS_BLK)     // 4096 points per block
#define PPT (SLICE / FPS_T)      // 8 points per thread, all coords in VGPRs
#define BQ_T 512
#define BQ_W 8      // waves per group block

// No mul+add contraction anywhere in this TU: per-op IEEE rounding must match
// the numpy reference exactly (((dx*dx + dy*dy) + dz*dz), each op rounded).
#pragma clang fp contract(off)

typedef float v2f __attribute__((ext_vector_type(2)));
typedef unsigned long long u64;

// 64-bit max-combine with a DPP-shifted copy of vv (old=0 == identity for max).
#define DPP64_MAXSTEP(vv, ctrl, rmask)                                          \
  {                                                                             \
    unsigned _lo = (unsigned)__builtin_amdgcn_update_dpp(                       \
        0, (int)(unsigned)((vv) & 0xffffffffull), (ctrl), (rmask), 0xf, false); \
    unsigned _hi = (unsigned)__builtin_amdgcn_update_dpp(                       \
        0, (int)(unsigned)((vv) >> 32), (ctrl), (rmask), 0xf, false);           \
    u64 _tv = ((u64)_hi << 32) | _lo;                                           \
    if (_tv > (vv)) (vv) = _tv;                                                 \
  }

// Exact-rounding distance^2, matching numpy: ((dx*dx + dy*dy) + dz*dz), no FMA.
__device__ __forceinline__ float dist2(float x, float y, float z,
                                       float cx, float cy, float cz) {
    float dx = __fsub_rn(x, cx);
    float dy = __fsub_rn(y, cy);
    float dz = __fsub_rn(z, cz);
    return __fadd_rn(__fadd_rn(__fmul_rn(dx, dx), __fmul_rn(dy, dy)),
                     __fmul_rn(dz, dz));
}

// ---------------------------------------------------------------------------
// Kernel 0: zero the cross-block slots + gl (ws is poisoned 0xAA; must be
// stream-ordered BEFORE fps so no block can see poison as a valid tag).
// ---------------------------------------------------------------------------
__global__ void init_kernel(u64* __restrict__ slots, int* __restrict__ gl) {
    int t = threadIdx.x;                 // 1024 threads
#pragma unroll
    for (int i = 0; i < (B_ * G_ * FPS_BLK * 4) / 1024; i++)
        slots[i * 1024 + t] = 0ull;
    if (t < B_) gl[t] = 0;
}

// ---------------------------------------------------------------------------
// Kernel 1: FPS, 4 blocks per batch (4096 pts each) + fused CNMS (slice 0).
//
// r19 post-mortem of r18 (205us best): chain is latency-bound (active-CU
// VALUBusy ~33%). The per-step p[n] center load is a CROSS-XCD miss (each
// block only staged its own slice through its XCD L2) costing ~400-600cyc
// strictly after the merge. Fix: pass the winner's COORDS through the slots.
// Winning thread self-identifies after the block reduce, extracts xyz via a
// static cndmask tree, publishes three tagged u64s {x|tag,y|tag,z|tag}
// (independent relaxed agent stores; pollers spin until all 3 tags nonzero
// => no ordering/128b-atomicity assumptions). Cross-block value-ties resolve
// by smallest slice == smallest n (slices partition n ascending); in-block
// ties by the u64 ladder's ~local_n. The point index n is never needed again.
// ---------------------------------------------------------------------------
__global__ __launch_bounds__(FPS_T, 2) void fps_cnms_kernel(
    const float4* __restrict__ pts, const int* __restrict__ lengths,
    float* __restrict__ centers_out, int* __restrict__ keep_out,
    u64* __restrict__ slots) {
    const int b = blockIdx.x & 7;        // batch (blocks of b share an XCD)
    const int slice = blockIdx.x >> 3;   // 0..3
    const int t = threadIdx.x;
    const int lane = t & 63;
    const int wv = t >> 6;               // 0..7
    const int len = lengths[b];
    const float4* p = pts + (size_t)b * N_;
    const int base = slice * SLICE;

    __shared__ __align__(16) u64 s_part[2][FPS_W];
    __shared__ float s_cen[G_][3];                        // centers (slice 0)

    // Stage all 8 points per thread into registers via opaque asm loads.
    // Pair j covers slots 2j (A) and 2j+1 (B); slot s is n = base + s*512 + t.
    v2f xp[PPT / 2], yp[PPT / 2], zp[PPT / 2];
    v2f mp[PPT / 2];
#pragma unroll
    for (int j = 0; j < PPT / 2; j += 2) {
        int nA0 = base + (2 * j) * FPS_T + t;
        float4 qA0, qB0, qA1, qB1;
        const float4* a0 = p + nA0;
        const float4* b0 = a0 + FPS_T;
        const float4* a1 = a0 + 2 * FPS_T;
        const float4* b1 = a0 + 3 * FPS_T;
        asm volatile(
            "global_load_dwordx4 %0, %4, off\n\t"
            "global_load_dwordx4 %1, %5, off\n\t"
            "global_load_dwordx4 %2, %6, off\n\t"
            "global_load_dwordx4 %3, %7, off\n\t"
            "s_waitcnt vmcnt(0)"
            : "=&v"(qA0), "=&v"(qB0), "=&v"(qA1), "=&v"(qB1)
            : "v"(a0), "v"(b0), "v"(a1), "v"(b1)
            : "memory");
        xp[j]     = (v2f){qA0.x, qB0.x};
        yp[j]     = (v2f){qA0.y, qB0.y};
        zp[j]     = (v2f){qA0.z, qB0.z};
        xp[j + 1] = (v2f){qA1.x, qB1.x};
        yp[j + 1] = (v2f){qA1.y, qB1.y};
        zp[j + 1] = (v2f){qA1.z, qB1.z};
        v2f mm0, mm1;
        mm0.x = (nA0 < len)             ? INFINITY : -INFINITY;
        mm0.y = (nA0 + FPS_T < len)     ? INFINITY : -INFINITY;
        mm1.x = (nA0 + 2 * FPS_T < len) ? INFINITY : -INFINITY;
        mm1.y = (nA0 + 3 * FPS_T < len) ? INFINITY : -INFINITY;
        mp[j] = mm0;
        mp[j + 1] = mm1;
    }

    // First center = point 0 (one-time load; only step that needs p[] again).
    float4 c0 = p[0];
    float cx = c0.x, cy = c0.y, cz = c0.z;

    for (int k = 0; k < G_; k++) {
        if (slice == 0 && t == 0) {
            centers_out[(b * G_ + k) * 3 + 0] = cx;
            centers_out[(b * G_ + k) * 3 + 1] = cy;
            centers_out[(b * G_ + k) * 3 + 2] = cz;
            s_cen[k][0] = cx; s_cen[k][1] = cy; s_cen[k][2] = cz;
        }
        if (k == G_ - 1) break;   // last argmax is discarded by the reference

        v2f cXX = {cx, cx};
        v2f cYY = {cy, cy};
        v2f cZZ = {cz, cz};

        // Min-only inner loop: pure-register, ~9 pk + 1 pk_min per point-pair.
#pragma unroll
        for (int j = 0; j < PPT / 2; j++) {
            v2f dx = xp[j] - cXX;
            v2f dy = yp[j] - cYY;
            v2f dz = zp[j] - cZZ;
            v2f dd = (dx * dx + dy * dy) + dz * dz;       // contract(off): exact
            mp[j] = __builtin_elementwise_min(mp[j], dd);
        }

        // Deferred thread-local value max (balanced tree).
        v2f t2a = __builtin_elementwise_max(mp[0], mp[1]);
        v2f t2b = __builtin_elementwise_max(mp[2], mp[3]);
        v2f t1  = __builtin_elementwise_max(t2a, t2b);
        float bv = fmaxf(t1.x, t1.y);

        // Smallest slot holding bv (even slot .x < odd slot .y in a pair).
        int bi = 0;
#pragma unroll
        for (int j = PPT / 2 - 1; j >= 0; j--) {
            bool hx = (mp[j].x == bv);
            bool hy = (mp[j].y == bv);
            int cand = 2 * j + (hx ? 0 : 1);
            if (hx || hy) bi = cand;
        }

        // Monotone u32 key of bv (never 0 for non-NaN, incl. +-inf).
        unsigned u = __float_as_uint(bv);
        u = (u & 0x80000000u) ? ~u : (u | 0x80000000u);
        int bn = (bi << 9) | t;           // LOCAL index (slice offset implicit)
        u64 v = ((u64)u << 32) | (unsigned)(~bn);

        // Wave argmax: u64 max == (max value, then min local index).
        DPP64_MAXSTEP(v, 0x111, 0xf);     // row_shl 1
        DPP64_MAXSTEP(v, 0x112, 0xf);     // row_shl 2
        DPP64_MAXSTEP(v, 0x114, 0xf);     // row_shl 4
        DPP64_MAXSTEP(v, 0x118, 0xf);     // row_shl 8
        DPP64_MAXSTEP(v, 0x142, 0xa);     // row_bcast15
        DPP64_MAXSTEP(v, 0x143, 0xc);     // row_bcast31 -> lane63 has wave max
        if (lane == 63) s_part[k & 1][wv] = v;
        __syncthreads();

        // Octet reduce of the 8 partials -> block key kk (all threads).
        u64 m = s_part[k & 1][lane & 7];
        DPP64_MAXSTEP(m, 0x111, 0xf);
        DPP64_MAXSTEP(m, 0x112, 0xf);
        DPP64_MAXSTEP(m, 0x114, 0xf);
        unsigned klo = (unsigned)__builtin_amdgcn_readlane(
            (int)(unsigned)(m & 0xffffffffull), 7);
        unsigned khi = (unsigned)__builtin_amdgcn_readlane(
            (int)(unsigned)(m >> 32), 7);

        // Winning thread publishes its winner's coords as 3 tagged u64s.
        unsigned kb = ~klo;               // (bi*512 | t) of block winner
        u64* slot = slots + (((size_t)b * G_ + k) * FPS_BLK + slice) * 4;
        if (t == (int)(kb & 511)) {
            int bis = (kb >> 9) & 7;
            v2f sx = (bis & 4) ? ((bis & 2) ? xp[3] : xp[2])
                               : ((bis & 2) ? xp[1] : xp[0]);
            v2f sy = (bis & 4) ? ((bis & 2) ? yp[3] : yp[2])
                               : ((bis & 2) ? yp[1] : yp[0]);
            v2f sz = (bis & 4) ? ((bis & 2) ? zp[3] : zp[2])
                               : ((bis & 2) ? zp[1] : zp[0]);
            float wx = (bis & 1) ? sx.y : sx.x;
            float wy = (bis & 1) ? sy.y : sy.x;
            float wz = (bis & 1) ? sz.y : sz.x;
            u64 ax = ((u64)__float_as_uint(wx) << 32) | khi;
            u64 ay = ((u64)__float_as_uint(wy) << 32) | khi;
            u64 az = ((u64)__float_as_uint(wz) << 32) | khi;
            __hip_atomic_store(&slot[0], ax, __ATOMIC_RELAXED,
                               __HIP_MEMORY_SCOPE_AGENT);
            __hip_atomic_store(&slot[1], ay, __ATOMIC_RELAXED,
                               __HIP_MEMORY_SCOPE_AGENT);
            __hip_atomic_store(&slot[2], az, __ATOMIC_RELAXED,
                               __HIP_MEMORY_SCOPE_AGENT);
        }

        // Lanes 0..3 poll the 4 slots (own included: parallel with remotes,
        // avoids a second barrier). All three tags nonzero => values final.
        unsigned tag = 0; float wx = 0.f, wy = 0.f, wz = 0.f; int slc = 3;
        if (lane < FPS_BLK) {
            const u64* s3 = slots + (((size_t)b * G_ + k) * FPS_BLK + lane) * 4;
            u64 ax, ay, az;
            do {
                ax = __hip_atomic_load(&s3[0], __ATOMIC_RELAXED,
                                       __HIP_MEMORY_SCOPE_AGENT);
                ay = __hip_atomic_load(&s3[1], __ATOMIC_RELAXED,
                                       __HIP_MEMORY_SCOPE_AGENT);
                az = __hip_atomic_load(&s3[2], __ATOMIC_RELAXED,
                                       __HIP_MEMORY_SCOPE_AGENT);
            } while (((unsigned)ax == 0u) | ((unsigned)ay == 0u) |
                     ((unsigned)az == 0u));
            tag = (unsigned)ax;
            wx = __uint_as_float((unsigned)(ax >> 32));
            wy = __uint_as_float((unsigned)(ay >> 32));
            wz = __uint_as_float((unsigned)(az >> 32));
            slc = lane;
        }
        // Butterfly merge over lanes 0..3: max tag, tie -> smaller slice.
#pragma unroll
        for (int mm = 1; mm <= 2; mm <<= 1) {
            unsigned otag = (unsigned)__shfl_xor((int)tag, mm);
            int oslc = __shfl_xor(slc, mm);
            float ox = __shfl_xor(wx, mm);
            float oy = __shfl_xor(wy, mm);
            float oz = __shfl_xor(wz, mm);
            bool take = (otag > tag) || (otag == tag && oslc < slc);
            tag = take ? otag : tag;
            slc = take ? oslc : slc;
            wx = take ? ox : wx;
            wy = take ? oy : wy;
            wz = take ? oz : wz;
        }
        cx = __uint_as_float((unsigned)__builtin_amdgcn_readfirstlane(
            (int)__float_as_uint(wx)));
        cy = __uint_as_float((unsigned)__builtin_amdgcn_readfirstlane(
            (int)__float_as_uint(wy)));
        cz = __uint_as_float((unsigned)__builtin_amdgcn_readfirstlane(
            (int)__float_as_uint(wz)));
    }

    __syncthreads();   // s_cen[127] written by t==0 after the break

    // ---- fused CNMS on wave 0 of the slice-0 block ----
    if (slice == 0 && t < 64) {
        const float THR = (float)((2.0 * 0.1 * (1.0 - 0.7)) * (2.0 * 0.1 * (1.0 - 0.7)));
        float ax = s_cen[t][0],      ay = s_cen[t][1],      az = s_cen[t][2];
        float ex = s_cen[t + 64][0], ey = s_cen[t + 64][1], ez = s_cen[t + 64][2];
        bool k0 = false, k1 = false;
        for (int j = 0; j < G_; j++) {
            float jx = s_cen[j][0], jy = s_cen[j][1], jz = s_cen[j][2];
            bool c0 = k0 && (dist2(ax, ay, az, jx, jy, jz) < THR);
            bool c1 = k1 && (dist2(ex, ey, ez, jx, jy, jz) < THR);
            bool conflict = __any(c0 || c1);
            if (j == t)      k0 = !conflict;
            if (j == t + 64) k1 = !conflict;
        }
        keep_out[b * G_ + t]      = k0 ? 1 : 0;
        keep_out[b * G_ + t + 64] = k1 ? 1 : 0;
    }
}

// ---------------------------------------------------------------------------
// Kernel 2: per-(b,g) ball query (first 128 by index) + top-32 by energy +
// gather/normalize. One 512-thread block per group. (unchanged)
// ---------------------------------------------------------------------------
__global__ __launch_bounds__(BQ_T) void group_kernel(
    const float4* __restrict__ pts, const int* __restrict__ lengths,
    const float* __restrict__ centers, const int* __restrict__ keep,
    float* __restrict__ groups_out, int* __restrict__ gl) {
    const int bid = blockIdx.x;          // b*128 + g
    const int b = bid >> 7;
    const int t = threadIdx.x;
    const int lane = t & 63;
    const int wv = t >> 6;

    const float cx = centers[bid * 3 + 0];
    const float cy = centers[bid * 3 + 1];
    const float cz = centers[bid * 3 + 2];
    float4* out4 = (float4*)(groups_out + (size_t)bid * GS_ * 4);

    if (!keep[bid]) {
        if (t < GS_) {
            float4 o;
            o.x = __fdiv_rn(__fsub_rn(0.f, cx), 0.1f);
            o.y = __fdiv_rn(__fsub_rn(0.f, cy), 0.1f);
            o.z = __fdiv_rn(__fsub_rn(0.f, cz), 0.1f);
            o.w = 0.f;
            out4[t] = o;
        }
        return;
    }

    __shared__ int   s_widx[BQ_W][UK_];
    __shared__ float s_wen[BQ_W][UK_];
    __shared__ int   s_wcnt[BQ_W];
    __shared__ int   s_list[UK_];
    __shared__ float s_en[UK_];
    __shared__ int   s_ord[GS_];

    const int len = lengths[b];
    const float R2 = (float)(0.1 * 0.1);
    const float4* p = pts + (size_t)b * N_;

    // Per-wave ordered stream compaction over its contiguous eighth.
    {
        const int base0 = wv * (N_ / BQ_W);
        int cnt = 0;
        for (int it = 0; it < (N_ / BQ_W) / 64; it++) {
            int n = base0 + it * 64 + lane;
            float4 q = p[n];
            float d2 = dist2(q.x, q.y, q.z, cx, cy, cz);
            bool pred = (n < len) && (d2 <= R2);
            unsigned long long m = __ballot(pred);
            int prefix = __popcll(m & ((1ull << lane) - 1ull));
            int slot = cnt + prefix;
            if (pred && slot < UK_) { s_widx[wv][slot] = n; s_wen[wv][slot] = q.w; }
            cnt += __popcll(m);
        }
        if (lane == 0) s_wcnt[wv] = (cnt < UK_) ? cnt : UK_;
    }
    __syncthreads();

    int M = 0;
#pragma unroll
    for (int w = 0; w < BQ_W; w++) M += s_wcnt[w];
    if (M > UK_) M = UK_;

    // Ordered merge into unified first-M list.
    if (t < UK_ && t < M) {
        int j = t, w = 0;
        while (w < BQ_W - 1 && j >= s_wcnt[w]) { j -= s_wcnt[w]; w++; }
        s_list[t] = s_widx[w][j];
        s_en[t]   = s_wen[w][j];
    }
    __syncthreads();

    // top-32 by energy, tie -> smaller list position (matches lax.top_k)
    if (wv == 0) {
        float v0 = (lane < M) ? s_en[lane] : -INFINITY;
        float v1 = (lane + 64 < M) ? s_en[lane + 64] : -INFINITY;
        for (int k = 0; k < GS_; k++) {
            float bv; int bs;
            if (v0 >= v1) { bv = v0; bs = lane; }
            else          { bv = v1; bs = lane + 64; }
#pragma unroll
            for (int off = 32; off; off >>= 1) {
                float ov = __shfl_xor(bv, off);
                int   os = __shfl_xor(bs, off);
                bool tk = (ov > bv) || (ov == bv && os < bs);
                bv = tk ? ov : bv; bs = tk ? os : bs;
            }
            if (lane == 0) s_ord[k] = (bv == -INFINITY) ? -1 : bs;
            if (bs == lane)           v0 = -INFINITY;
            else if (bs == lane + 64) v1 = -INFINITY;
        }
    }
    __syncthreads();

    if (t < GS_) {
        int o0 = s_ord[0];
        int first = (o0 >= 0) ? s_list[o0] : -1;
        int ok = s_ord[t];
        int ti = (ok >= 0) ? s_list[ok] : -1;
        int f = (ti == -1) ? first : ti;
        float px = 0.f, py = 0.f, pz = 0.f, pw = 0.f;
        if (f >= 0) { float4 q = p[f]; px = q.x; py = q.y; pz = q.z; pw = q.w; }
        float4 o;
        o.x = __fdiv_rn(__fsub_rn(px, cx), 0.1f);
        o.y = __fdiv_rn(__fsub_rn(py, cy), 0.1f);
        o.z = __fdiv_rn(__fsub_rn(pz, cz), 0.1f);
        o.w = __fdiv_rn(pw, 0.1f);
        out4[t] = o;
    }
    if (t == 0 && M >= GS_) atomicAdd(&gl[b], 1);
}

// ---------------------------------------------------------------------------
// Kernel 3: embedding mask
// ---------------------------------------------------------------------------
__global__ void mask_kernel(const int* __restrict__ gl, float* __restrict__ mask_out) {
    int t = threadIdx.x;                 // 1024 threads
    int b = t >> 7, g = t & 127;
    mask_out[t] = (g < gl[b]) ? 1.0f : 0.0f;
}

extern "C" void kernel_launch(void* const* d_in, const int* in_sizes, int n_in,
                              void* d_out, int out_size, void* d_ws, size_t ws_size,
                              hipStream_t stream) {
    const float4* pts = (const float4*)d_in[0];
    const int* lengths = (const int*)d_in[1];
    float* out = (float*)d_out;
    float* groups = out;                               // B*G*GS*4 = 131072
    float* centers = out + (size_t)B_ * G_ * GS_ * 4;  // +3072
    float* mask = centers + (size_t)B_ * G_ * 3;       // +1024
    u64* slots = (u64*)d_ws;                           // B*G*FPS_BLK*4 u64
    int* keep = (int*)(slots + B_ * G_ * FPS_BLK * 4); // B*G ints
    int* gl = keep + B_ * G_;                          // B ints

    hipLaunchKernelGGL(init_kernel, dim3(1), dim3(1024), 0, stream, slots, gl);
    hipLaunchKernelGGL(fps_cnms_kernel, dim3(B_ * FPS_BLK), dim3(FPS_T), 0, stream,
                       pts, lengths, centers, keep, slots);
    hipLaunchKernelGGL(group_kernel, dim3(B_ * G_), dim3(BQ_T), 0, stream,
                       pts, lengths, centers, keep, groups, gl);
    hipLaunchKernelGGL(mask_kernel, dim3(1), dim3(B_ * G_), 0, stream, gl, mask);
}

// Round 10
// 300.591 us; speedup vs baseline: 1.1444x; 1.1444x over previous
//
#include <hip/hip_runtime.h>
#include <math.h>

#define B_ 8
#define N_ 16384
#define G_ 128      // NUM_GROUPS
#define GS_ 32      // GROUP_SIZE
#define UK_ 128     // UPSCALE_K
#define FPS_T 512
#define FPS_W 8     // waves per FPS block
#define FPS_BLK 4   // blocks (slices) per batch, stride-8 blockIdx => same XCD
#define SLICE (N_ / FPS_BLK)     // 4096 points per block
#define PPT (SLICE / FPS_T)      // 8 points per thread, all coords in VGPRs
#define BQ_T 512
#define BQ_W 8      // waves per group block

// No mul+add contraction anywhere in this TU: per-op IEEE rounding must match
// the numpy reference exactly (((dx*dx + dy*dy) + dz*dz), each op rounded).
#pragma clang fp contract(off)

typedef float v2f __attribute__((ext_vector_type(2)));
typedef unsigned long long u64;

// 64-bit max-combine with a DPP-shifted copy of vv (old=0 == identity for max).
#define DPP64_MAXSTEP(vv, ctrl, rmask)                                          \
  {                                                                             \
    unsigned _lo = (unsigned)__builtin_amdgcn_update_dpp(                       \
        0, (int)(unsigned)((vv) & 0xffffffffull), (ctrl), (rmask), 0xf, false); \
    unsigned _hi = (unsigned)__builtin_amdgcn_update_dpp(                       \
        0, (int)(unsigned)((vv) >> 32), (ctrl), (rmask), 0xf, false);           \
    u64 _tv = ((u64)_hi << 32) | _lo;                                           \
    if (_tv > (vv)) (vv) = _tv;                                                 \
  }

__device__ __forceinline__ u64 shfl_xor_u64(u64 v, int m) {
    int lo = __shfl_xor((int)(unsigned)(v & 0xffffffffull), m);
    int hi = __shfl_xor((int)(unsigned)(v >> 32), m);
    return ((u64)(unsigned)hi << 32) | (unsigned)lo;
}

__device__ __forceinline__ u64 umax64(u64 a, u64 b) { return a > b ? a : b; }

// Exact-rounding distance^2, matching numpy: ((dx*dx + dy*dy) + dz*dz), no FMA.
__device__ __forceinline__ float dist2(float x, float y, float z,
                                       float cx, float cy, float cz) {
    float dx = __fsub_rn(x, cx);
    float dy = __fsub_rn(y, cy);
    float dz = __fsub_rn(z, cz);
    return __fadd_rn(__fadd_rn(__fmul_rn(dx, dx), __fmul_rn(dy, dy)),
                     __fmul_rn(dz, dz));
}

// ---------------------------------------------------------------------------
// Kernel 0: zero the cross-block slots + gl + done (ws is poisoned 0xAA; must
// be stream-ordered BEFORE fps/group so no block can see poison).
// ---------------------------------------------------------------------------
__global__ void init_kernel(u64* __restrict__ slots, int* __restrict__ gl,
                            int* __restrict__ done) {
    int t = threadIdx.x;                 // 1024 threads
#pragma unroll
    for (int i = 0; i < (B_ * G_ * FPS_BLK) / 1024; i++)
        slots[i * 1024 + t] = 0ull;
    if (t < B_) { gl[t] = 0; done[t] = 0; }
}

// ---------------------------------------------------------------------------
// Kernel 1: FPS, 4 blocks per batch (4096 pts each) + fused CNMS (slice 0).
// EXACT r18 structure (205us proven): r19's coord-passing regressed (3 tagged
// stores + 3-load poll > one own-XCD-L2 p[n] load). AGENT-scope slot ops have
// a ~2-LLC-RTT floor; this is the structure's latency floor.
// ---------------------------------------------------------------------------
__global__ __launch_bounds__(FPS_T, 2) void fps_cnms_kernel(
    const float4* __restrict__ pts, const int* __restrict__ lengths,
    float* __restrict__ centers_out, int* __restrict__ keep_out,
    u64* __restrict__ slots) {
    const int b = blockIdx.x & 7;        // batch (blocks of b share an XCD)
    const int slice = blockIdx.x >> 3;   // 0..3
    const int t = threadIdx.x;
    const int lane = t & 63;
    const int wv = t >> 6;               // 0..7
    const int len = lengths[b];
    const float4* p = pts + (size_t)b * N_;
    const int base = slice * SLICE;

    __shared__ __align__(16) u64 s_part[2][FPS_W];
    __shared__ float s_cen[G_][3];                        // centers (slice 0)

    // Stage all 8 points per thread into registers via opaque asm loads
    // (compiler cannot rematerialize volatile-asm outputs; 24 payload regs).
    // Pair j covers slots 2j (A) and 2j+1 (B); slot s is n = base + s*512 + t.
    v2f xp[PPT / 2], yp[PPT / 2], zp[PPT / 2];
    v2f mp[PPT / 2];
#pragma unroll
    for (int j = 0; j < PPT / 2; j += 2) {
        int nA0 = base + (2 * j) * FPS_T + t;
        float4 qA0, qB0, qA1, qB1;
        const float4* a0 = p + nA0;
        const float4* b0 = a0 + FPS_T;
        const float4* a1 = a0 + 2 * FPS_T;
        const float4* b1 = a0 + 3 * FPS_T;
        asm volatile(
            "global_load_dwordx4 %0, %4, off\n\t"
            "global_load_dwordx4 %1, %5, off\n\t"
            "global_load_dwordx4 %2, %6, off\n\t"
            "global_load_dwordx4 %3, %7, off\n\t"
            "s_waitcnt vmcnt(0)"
            : "=&v"(qA0), "=&v"(qB0), "=&v"(qA1), "=&v"(qB1)
            : "v"(a0), "v"(b0), "v"(a1), "v"(b1)
            : "memory");
        xp[j]     = (v2f){qA0.x, qB0.x};
        yp[j]     = (v2f){qA0.y, qB0.y};
        zp[j]     = (v2f){qA0.z, qB0.z};
        xp[j + 1] = (v2f){qA1.x, qB1.x};
        yp[j + 1] = (v2f){qA1.y, qB1.y};
        zp[j + 1] = (v2f){qA1.z, qB1.z};
        v2f mm0, mm1;
        mm0.x = (nA0 < len)             ? INFINITY : -INFINITY;
        mm0.y = (nA0 + FPS_T < len)     ? INFINITY : -INFINITY;
        mm1.x = (nA0 + 2 * FPS_T < len) ? INFINITY : -INFINITY;
        mm1.y = (nA0 + 3 * FPS_T < len) ? INFINITY : -INFINITY;
        mp[j] = mm0;
        mp[j + 1] = mm1;
    }

    int n = 0;   // winner index (uniform across ALL blocks of batch b)
    for (int k = 0; k < G_; k++) {
        float4 c = p[n];   // uniform broadcast load (own-XCD L2)
        if (slice == 0 && t == 0) {
            centers_out[(b * G_ + k) * 3 + 0] = c.x;
            centers_out[(b * G_ + k) * 3 + 1] = c.y;
            centers_out[(b * G_ + k) * 3 + 2] = c.z;
            s_cen[k][0] = c.x; s_cen[k][1] = c.y; s_cen[k][2] = c.z;
        }
        if (k == G_ - 1) break;   // last argmax is discarded by the reference

        v2f cXX = {c.x, c.x};
        v2f cYY = {c.y, c.y};
        v2f cZZ = {c.z, c.z};

        // Min-only inner loop: pure-register, 8 pk + 2 v_min per point-pair.
#pragma unroll
        for (int j = 0; j < PPT / 2; j++) {
            v2f dx = xp[j] - cXX;
            v2f dy = yp[j] - cYY;
            v2f dz = zp[j] - cZZ;
            v2f dd = (dx * dx + dy * dy) + dz * dz;       // contract(off): exact
            mp[j] = __builtin_elementwise_min(mp[j], dd);
        }

        // Deferred thread-local value max (balanced tree).
        v2f t2a = __builtin_elementwise_max(mp[0], mp[1]);
        v2f t2b = __builtin_elementwise_max(mp[2], mp[3]);
        v2f t1  = __builtin_elementwise_max(t2a, t2b);
        float bv = fmaxf(t1.x, t1.y);

        // Smallest slot holding bv (even slot .x < odd slot .y in a pair).
        int bi = 0;
#pragma unroll
        for (int j = PPT / 2 - 1; j >= 0; j--) {
            bool hx = (mp[j].x == bv);
            bool hy = (mp[j].y == bv);
            int cand = 2 * j + (hx ? 0 : 1);
            if (hx || hy) bi = cand;
        }

        // Monotone u32 key of bv (never 0 for non-NaN, incl. +-inf).
        unsigned u = __float_as_uint(bv);
        u = (u & 0x80000000u) ? ~u : (u | 0x80000000u);
        int bn = base | (bi << 9) | t;    // global point index in batch
        u64 v = ((u64)u << 32) | (unsigned)(~bn);

        // Wave argmax: u64 max == (max value, then min index among ties).
        DPP64_MAXSTEP(v, 0x111, 0xf);     // row_shl 1
        DPP64_MAXSTEP(v, 0x112, 0xf);     // row_shl 2
        DPP64_MAXSTEP(v, 0x114, 0xf);     // row_shl 4
        DPP64_MAXSTEP(v, 0x118, 0xf);     // row_shl 8
        DPP64_MAXSTEP(v, 0x142, 0xa);     // row_bcast15
        DPP64_MAXSTEP(v, 0x143, 0xc);     // row_bcast31 -> lane63 has wave max
        if (lane == 63) s_part[k & 1][wv] = v;
        __syncthreads();

        // Every wave redundantly reduces the 8 partials (3 DPP steps) -> block
        // key kk, then polls the 3 REMOTE slots itself (lane==slice keeps kk).
        // One barrier per step; double-buffered s_part is race-free.
        u64 m = s_part[k & 1][lane & 7];
        DPP64_MAXSTEP(m, 0x111, 0xf);
        DPP64_MAXSTEP(m, 0x112, 0xf);
        DPP64_MAXSTEP(m, 0x114, 0xf);
        unsigned klo = (unsigned)__builtin_amdgcn_readlane(
            (int)(unsigned)(m & 0xffffffffull), 7);
        unsigned khi = (unsigned)__builtin_amdgcn_readlane(
            (int)(unsigned)(m >> 32), 7);
        u64 kk = ((u64)khi << 32) | klo;

        u64* slot = slots + ((size_t)b * G_ + k) * FPS_BLK;
        if (wv == 0 && lane == 0)
            __hip_atomic_store(&slot[slice], kk, __ATOMIC_RELAXED,
                               __HIP_MEMORY_SCOPE_AGENT);
        u64 pv = kk;                      // own block's key for lane==slice
        if (lane < FPS_BLK && lane != slice) {
            do {
                pv = __hip_atomic_load(&slot[lane], __ATOMIC_RELAXED,
                                       __HIP_MEMORY_SCOPE_AGENT);
            } while (pv == 0ull);
        }
        // Merge lanes 0..3; lane0's result is the global winner; broadcast.
        u64 mg = umax64(pv, shfl_xor_u64(pv, 1));
        mg = umax64(mg, shfl_xor_u64(mg, 2));
        unsigned wlo = (unsigned)__builtin_amdgcn_readfirstlane(
            (int)(unsigned)(mg & 0xffffffffull));
        n = (int)(~wlo);                  // decode index
    }

    __syncthreads();   // s_cen[127] written by t==0 after the break

    // ---- fused CNMS on wave 0 of the slice-0 block ----
    if (slice == 0 && t < 64) {
        const float THR = (float)((2.0 * 0.1 * (1.0 - 0.7)) * (2.0 * 0.1 * (1.0 - 0.7)));
        float ax = s_cen[t][0],      ay = s_cen[t][1],      az = s_cen[t][2];
        float ex = s_cen[t + 64][0], ey = s_cen[t + 64][1], ez = s_cen[t + 64][2];
        bool k0 = false, k1 = false;
        for (int j = 0; j < G_; j++) {
            float jx = s_cen[j][0], jy = s_cen[j][1], jz = s_cen[j][2];
            bool c0 = k0 && (dist2(ax, ay, az, jx, jy, jz) < THR);
            bool c1 = k1 && (dist2(ex, ey, ez, jx, jy, jz) < THR);
            bool conflict = __any(c0 || c1);
            if (j == t)      k0 = !conflict;
            if (j == t + 64) k1 = !conflict;
        }
        keep_out[b * G_ + t]      = k0 ? 1 : 0;
        keep_out[b * G_ + t + 64] = k1 ? 1 : 0;
    }
}

// ---------------------------------------------------------------------------
// Kernel 2: per-(b,g) ball query + top-32 + gather/normalize + fused mask.
// r20: blocks are XCD-aligned to their batch (b = blockIdx%8) so the point
// reads hit the XCD L2 that fps just warmed (was: sprayed across all 8 XCDs
// => LLC reads). mask_kernel is fused via a per-batch done-counter: the 128th
// finishing block of batch b writes the mask row (device-scope atomics +
// threadfence; dispatch-order independent).
// ---------------------------------------------------------------------------
__global__ __launch_bounds__(BQ_T) void group_kernel(
    const float4* __restrict__ pts, const int* __restrict__ lengths,
    const float* __restrict__ centers, const int* __restrict__ keep,
    float* __restrict__ groups_out, int* __restrict__ gl,
    int* __restrict__ done, float* __restrict__ mask_out) {
    const int bid = blockIdx.x;
    const int b = bid & 7;               // batch == blockIdx%8 == XCD (perf)
    const int g = bid >> 3;
    const int gid = b * G_ + g;
    const int t = threadIdx.x;
    const int lane = t & 63;
    const int wv = t >> 6;

    const float cx = centers[gid * 3 + 0];
    const float cy = centers[gid * 3 + 1];
    const float cz = centers[gid * 3 + 2];
    float4* out4 = (float4*)(groups_out + (size_t)gid * GS_ * 4);

    const bool kept = keep[gid] != 0;
    bool full = false;                   // M >= GS_ (kept path only)

    if (!kept) {
        if (t < GS_) {
            float4 o;
            o.x = __fdiv_rn(__fsub_rn(0.f, cx), 0.1f);
            o.y = __fdiv_rn(__fsub_rn(0.f, cy), 0.1f);
            o.z = __fdiv_rn(__fsub_rn(0.f, cz), 0.1f);
            o.w = 0.f;
            out4[t] = o;
        }
    } else {
        __shared__ int   s_widx[BQ_W][UK_];
        __shared__ float s_wen[BQ_W][UK_];
        __shared__ int   s_wcnt[BQ_W];
        __shared__ int   s_list[UK_];
        __shared__ float s_en[UK_];
        __shared__ int   s_ord[GS_];

        const int len = lengths[b];
        const float R2 = (float)(0.1 * 0.1);
        const float4* p = pts + (size_t)b * N_;

        // Per-wave ordered stream compaction over its contiguous eighth.
        {
            const int base0 = wv * (N_ / BQ_W);
            int cnt = 0;
            for (int it = 0; it < (N_ / BQ_W) / 64; it++) {
                int n = base0 + it * 64 + lane;
                float4 q = p[n];
                float d2 = dist2(q.x, q.y, q.z, cx, cy, cz);
                bool pred = (n < len) && (d2 <= R2);
                u64 m = __ballot(pred);
                int prefix = __popcll(m & ((1ull << lane) - 1ull));
                int slot = cnt + prefix;
                if (pred && slot < UK_) { s_widx[wv][slot] = n; s_wen[wv][slot] = q.w; }
                cnt += __popcll(m);
            }
            if (lane == 0) s_wcnt[wv] = (cnt < UK_) ? cnt : UK_;
        }
        __syncthreads();

        int M = 0;
#pragma unroll
        for (int w = 0; w < BQ_W; w++) M += s_wcnt[w];
        if (M > UK_) M = UK_;
        full = (M >= GS_);

        // Ordered merge into unified first-M list.
        if (t < UK_ && t < M) {
            int j = t, w = 0;
            while (w < BQ_W - 1 && j >= s_wcnt[w]) { j -= s_wcnt[w]; w++; }
            s_list[t] = s_widx[w][j];
            s_en[t]   = s_wen[w][j];
        }
        __syncthreads();

        // top-32 by energy, tie -> smaller list position (matches lax.top_k)
        if (wv == 0) {
            float v0 = (lane < M) ? s_en[lane] : -INFINITY;
            float v1 = (lane + 64 < M) ? s_en[lane + 64] : -INFINITY;
            for (int k = 0; k < GS_; k++) {
                float bv; int bs;
                if (v0 >= v1) { bv = v0; bs = lane; }
                else          { bv = v1; bs = lane + 64; }
#pragma unroll
                for (int off = 32; off; off >>= 1) {
                    float ov = __shfl_xor(bv, off);
                    int   os = __shfl_xor(bs, off);
                    bool tk = (ov > bv) || (ov == bv && os < bs);
                    bv = tk ? ov : bv; bs = tk ? os : bs;
                }
                if (lane == 0) s_ord[k] = (bv == -INFINITY) ? -1 : bs;
                if (bs == lane)           v0 = -INFINITY;
                else if (bs == lane + 64) v1 = -INFINITY;
            }
        }
        __syncthreads();

        if (t < GS_) {
            int o0 = s_ord[0];
            int first = (o0 >= 0) ? s_list[o0] : -1;
            int ok = s_ord[t];
            int ti = (ok >= 0) ? s_list[ok] : -1;
            int f = (ti == -1) ? first : ti;
            float px = 0.f, py = 0.f, pz = 0.f, pw = 0.f;
            if (f >= 0) { float4 q = p[f]; px = q.x; py = q.y; pz = q.z; pw = q.w; }
            float4 o;
            o.x = __fdiv_rn(__fsub_rn(px, cx), 0.1f);
            o.y = __fdiv_rn(__fsub_rn(py, cy), 0.1f);
            o.z = __fdiv_rn(__fsub_rn(pz, cz), 0.1f);
            o.w = __fdiv_rn(pw, 0.1f);
            out4[t] = o;
        }
    }

    // ---- fused mask: per-batch completion count; 128th block writes row b.
    if (wv == 0) {
        int old = 0;
        if (lane == 0) {
            if (kept && full) atomicAdd(&gl[b], 1);
            __threadfence();             // gl visible before done increment
            old = atomicAdd(&done[b], 1);
        }
        old = __shfl(old, 0);
        if (old == G_ - 1) {
            __threadfence();             // see all other blocks' gl adds
            int glb = __hip_atomic_load(&gl[b], __ATOMIC_RELAXED,
                                        __HIP_MEMORY_SCOPE_AGENT);
            mask_out[b * G_ + lane]      = (lane < glb) ? 1.0f : 0.0f;
            mask_out[b * G_ + 64 + lane] = (64 + lane < glb) ? 1.0f : 0.0f;
        }
    }
}

extern "C" void kernel_launch(void* const* d_in, const int* in_sizes, int n_in,
                              void* d_out, int out_size, void* d_ws, size_t ws_size,
                              hipStream_t stream) {
    const float4* pts = (const float4*)d_in[0];
    const int* lengths = (const int*)d_in[1];
    float* out = (float*)d_out;
    float* groups = out;                               // B*G*GS*4 = 131072
    float* centers = out + (size_t)B_ * G_ * GS_ * 4;  // +3072
    float* mask = centers + (size_t)B_ * G_ * 3;       // +1024
    u64* slots = (u64*)d_ws;                           // B*G*FPS_BLK u64
    int* keep = (int*)(slots + B_ * G_ * FPS_BLK);     // B*G ints
    int* gl = keep + B_ * G_;                          // B ints
    int* done = gl + B_;                               // B ints

    hipLaunchKernelGGL(init_kernel, dim3(1), dim3(1024), 0, stream, slots, gl, done);
    hipLaunchKernelGGL(fps_cnms_kernel, dim3(B_ * FPS_BLK), dim3(FPS_T), 0, stream,
                       pts, lengths, centers, keep, slots);
    hipLaunchKernelGGL(group_kernel, dim3(B_ * G_), dim3(BQ_T), 0, stream,
                       pts, lengths, centers, keep, groups, gl, done, mask);
}

// Round 11
// 289.889 us; speedup vs baseline: 1.1867x; 1.0369x over previous
//
#include <hip/hip_runtime.h>
#include <math.h>

#define B_ 8
#define N_ 16384
#define G_ 128      // NUM_GROUPS
#define GS_ 32      // GROUP_SIZE
#define UK_ 128     // UPSCALE_K
#define FPS_T 512
#define FPS_W 8     // waves per FPS block
#define FPS_BLK 4   // blocks (slices) per batch, stride-8 blockIdx => same XCD
#define SLICE (N_ / FPS_BLK)     // 4096 points per block
#define PPT (SLICE / FPS_T)      // 8 points per thread, all coords in VGPRs
#define BQ_T 512
#define BQ_W 8      // waves per group block

// No mul+add contraction anywhere in this TU: per-op IEEE rounding must match
// the numpy reference exactly (((dx*dx + dy*dy) + dz*dz), each op rounded).
#pragma clang fp contract(off)

typedef float v2f __attribute__((ext_vector_type(2)));
typedef unsigned long long u64;

// Valid slot keys are (mono_value<<32)|~bn with bn<16384, so the low word is
// >= 0xFFFFC000. Workspace poison (0xAA bytes -> low 0xAAAAAAAA) and zero both
// FAIL this test => no slot initialization pass is needed (init_kernel gone).
#define SLOT_VALID(pv) ((unsigned)(pv) >= 0xFFFFC000u)

// 64-bit max-combine with a DPP-shifted copy of vv (old=0 == identity for max).
#define DPP64_MAXSTEP(vv, ctrl, rmask)                                          \
  {                                                                             \
    unsigned _lo = (unsigned)__builtin_amdgcn_update_dpp(                       \
        0, (int)(unsigned)((vv) & 0xffffffffull), (ctrl), (rmask), 0xf, false); \
    unsigned _hi = (unsigned)__builtin_amdgcn_update_dpp(                       \
        0, (int)(unsigned)((vv) >> 32), (ctrl), (rmask), 0xf, false);           \
    u64 _tv = ((u64)_hi << 32) | _lo;                                           \
    if (_tv > (vv)) (vv) = _tv;                                                 \
  }

__device__ __forceinline__ u64 shfl_xor_u64(u64 v, int m) {
    int lo = __shfl_xor((int)(unsigned)(v & 0xffffffffull), m);
    int hi = __shfl_xor((int)(unsigned)(v >> 32), m);
    return ((u64)(unsigned)hi << 32) | (unsigned)lo;
}

__device__ __forceinline__ u64 umax64(u64 a, u64 b) { return a > b ? a : b; }

// Exact-rounding distance^2, matching numpy: ((dx*dx + dy*dy) + dz*dz), no FMA.
__device__ __forceinline__ float dist2(float x, float y, float z,
                                       float cx, float cy, float cz) {
    float dx = __fsub_rn(x, cx);
    float dy = __fsub_rn(y, cy);
    float dz = __fsub_rn(z, cz);
    return __fadd_rn(__fadd_rn(__fmul_rn(dx, dx), __fmul_rn(dy, dy)),
                     __fmul_rn(dz, dz));
}

// ---------------------------------------------------------------------------
// Kernel 1: FPS, 4 blocks per batch (4096 pts each) + fused CNMS (slice 0).
// EXACT r18 structure (205us proven; r19 coord-passing regressed, reverted).
// r21 deltas: (a) slot poll uses the SLOT_VALID sentinel instead of !=0, so
// the init_kernel zeroing pass is deleted (one fewer dispatch); (b) fps
// zeroes gl[b] (stream-ordered before group_kernel reads it).
// ---------------------------------------------------------------------------
__global__ __launch_bounds__(FPS_T, 2) void fps_cnms_kernel(
    const float4* __restrict__ pts, const int* __restrict__ lengths,
    float* __restrict__ centers_out, int* __restrict__ keep_out,
    u64* __restrict__ slots, int* __restrict__ gl) {
    const int b = blockIdx.x & 7;        // batch (blocks of b share an XCD)
    const int slice = blockIdx.x >> 3;   // 0..3
    const int t = threadIdx.x;
    const int lane = t & 63;
    const int wv = t >> 6;               // 0..7
    const int len = lengths[b];
    const float4* p = pts + (size_t)b * N_;
    const int base = slice * SLICE;

    if (slice == 0 && t == 0) gl[b] = 0;   // group_kernel's accumulator

    __shared__ __align__(16) u64 s_part[2][FPS_W];
    __shared__ float s_cen[G_][3];                        // centers (slice 0)

    // Stage all 8 points per thread into registers via opaque asm loads
    // (compiler cannot rematerialize volatile-asm outputs; 24 payload regs).
    // Pair j covers slots 2j (A) and 2j+1 (B); slot s is n = base + s*512 + t.
    v2f xp[PPT / 2], yp[PPT / 2], zp[PPT / 2];
    v2f mp[PPT / 2];
#pragma unroll
    for (int j = 0; j < PPT / 2; j += 2) {
        int nA0 = base + (2 * j) * FPS_T + t;
        float4 qA0, qB0, qA1, qB1;
        const float4* a0 = p + nA0;
        const float4* b0 = a0 + FPS_T;
        const float4* a1 = a0 + 2 * FPS_T;
        const float4* b1 = a0 + 3 * FPS_T;
        asm volatile(
            "global_load_dwordx4 %0, %4, off\n\t"
            "global_load_dwordx4 %1, %5, off\n\t"
            "global_load_dwordx4 %2, %6, off\n\t"
            "global_load_dwordx4 %3, %7, off\n\t"
            "s_waitcnt vmcnt(0)"
            : "=&v"(qA0), "=&v"(qB0), "=&v"(qA1), "=&v"(qB1)
            : "v"(a0), "v"(b0), "v"(a1), "v"(b1)
            : "memory");
        xp[j]     = (v2f){qA0.x, qB0.x};
        yp[j]     = (v2f){qA0.y, qB0.y};
        zp[j]     = (v2f){qA0.z, qB0.z};
        xp[j + 1] = (v2f){qA1.x, qB1.x};
        yp[j + 1] = (v2f){qA1.y, qB1.y};
        zp[j + 1] = (v2f){qA1.z, qB1.z};
        v2f mm0, mm1;
        mm0.x = (nA0 < len)             ? INFINITY : -INFINITY;
        mm0.y = (nA0 + FPS_T < len)     ? INFINITY : -INFINITY;
        mm1.x = (nA0 + 2 * FPS_T < len) ? INFINITY : -INFINITY;
        mm1.y = (nA0 + 3 * FPS_T < len) ? INFINITY : -INFINITY;
        mp[j] = mm0;
        mp[j + 1] = mm1;
    }

    int n = 0;   // winner index (uniform across ALL blocks of batch b)
    for (int k = 0; k < G_; k++) {
        float4 c = p[n];   // uniform broadcast load (own-XCD L2)
        if (slice == 0 && t == 0) {
            centers_out[(b * G_ + k) * 3 + 0] = c.x;
            centers_out[(b * G_ + k) * 3 + 1] = c.y;
            centers_out[(b * G_ + k) * 3 + 2] = c.z;
            s_cen[k][0] = c.x; s_cen[k][1] = c.y; s_cen[k][2] = c.z;
        }
        if (k == G_ - 1) break;   // last argmax is discarded by the reference

        v2f cXX = {c.x, c.x};
        v2f cYY = {c.y, c.y};
        v2f cZZ = {c.z, c.z};

        // Min-only inner loop: pure-register, 8 pk + 2 v_min per point-pair.
#pragma unroll
        for (int j = 0; j < PPT / 2; j++) {
            v2f dx = xp[j] - cXX;
            v2f dy = yp[j] - cYY;
            v2f dz = zp[j] - cZZ;
            v2f dd = (dx * dx + dy * dy) + dz * dz;       // contract(off): exact
            mp[j] = __builtin_elementwise_min(mp[j], dd);
        }

        // Deferred thread-local value max (balanced tree).
        v2f t2a = __builtin_elementwise_max(mp[0], mp[1]);
        v2f t2b = __builtin_elementwise_max(mp[2], mp[3]);
        v2f t1  = __builtin_elementwise_max(t2a, t2b);
        float bv = fmaxf(t1.x, t1.y);

        // Smallest slot holding bv (even slot .x < odd slot .y in a pair).
        int bi = 0;
#pragma unroll
        for (int j = PPT / 2 - 1; j >= 0; j--) {
            bool hx = (mp[j].x == bv);
            bool hy = (mp[j].y == bv);
            int cand = 2 * j + (hx ? 0 : 1);
            if (hx || hy) bi = cand;
        }

        // Monotone u32 key of bv (never 0 for non-NaN, incl. +-inf).
        unsigned u = __float_as_uint(bv);
        u = (u & 0x80000000u) ? ~u : (u | 0x80000000u);
        int bn = base | (bi << 9) | t;    // global point index in batch
        u64 v = ((u64)u << 32) | (unsigned)(~bn);

        // Wave argmax: u64 max == (max value, then min index among ties).
        DPP64_MAXSTEP(v, 0x111, 0xf);     // row_shl 1
        DPP64_MAXSTEP(v, 0x112, 0xf);     // row_shl 2
        DPP64_MAXSTEP(v, 0x114, 0xf);     // row_shl 4
        DPP64_MAXSTEP(v, 0x118, 0xf);     // row_shl 8
        DPP64_MAXSTEP(v, 0x142, 0xa);     // row_bcast15
        DPP64_MAXSTEP(v, 0x143, 0xc);     // row_bcast31 -> lane63 has wave max
        if (lane == 63) s_part[k & 1][wv] = v;
        __syncthreads();

        // Every wave redundantly reduces the 8 partials (3 DPP steps) -> block
        // key kk, then polls the 3 REMOTE slots itself (lane==slice keeps kk).
        // One barrier per step; double-buffered s_part is race-free.
        u64 m = s_part[k & 1][lane & 7];
        DPP64_MAXSTEP(m, 0x111, 0xf);
        DPP64_MAXSTEP(m, 0x112, 0xf);
        DPP64_MAXSTEP(m, 0x114, 0xf);
        unsigned klo = (unsigned)__builtin_amdgcn_readlane(
            (int)(unsigned)(m & 0xffffffffull), 7);
        unsigned khi = (unsigned)__builtin_amdgcn_readlane(
            (int)(unsigned)(m >> 32), 7);
        u64 kk = ((u64)khi << 32) | klo;

        u64* slot = slots + ((size_t)b * G_ + k) * FPS_BLK;
        if (wv == 0 && lane == 0)
            __hip_atomic_store(&slot[slice], kk, __ATOMIC_RELAXED,
                               __HIP_MEMORY_SCOPE_AGENT);
        u64 pv = kk;                      // own block's key for lane==slice
        if (lane < FPS_BLK && lane != slice) {
            do {
                pv = __hip_atomic_load(&slot[lane], __ATOMIC_RELAXED,
                                       __HIP_MEMORY_SCOPE_AGENT);
            } while (!SLOT_VALID(pv));    // poison/zero fail; real keys pass
        }
        // Merge lanes 0..3; lane0's result is the global winner; broadcast.
        u64 mg = umax64(pv, shfl_xor_u64(pv, 1));
        mg = umax64(mg, shfl_xor_u64(mg, 2));
        unsigned wlo = (unsigned)__builtin_amdgcn_readfirstlane(
            (int)(unsigned)(mg & 0xffffffffull));
        n = (int)(~wlo);                  // decode index
    }

    __syncthreads();   // s_cen[127] written by t==0 after the break

    // ---- fused CNMS on wave 0 of the slice-0 block ----
    if (slice == 0 && t < 64) {
        const float THR = (float)((2.0 * 0.1 * (1.0 - 0.7)) * (2.0 * 0.1 * (1.0 - 0.7)));
        float ax = s_cen[t][0],      ay = s_cen[t][1],      az = s_cen[t][2];
        float ex = s_cen[t + 64][0], ey = s_cen[t + 64][1], ez = s_cen[t + 64][2];
        bool k0 = false, k1 = false;
        for (int j = 0; j < G_; j++) {
            float jx = s_cen[j][0], jy = s_cen[j][1], jz = s_cen[j][2];
            bool c0 = k0 && (dist2(ax, ay, az, jx, jy, jz) < THR);
            bool c1 = k1 && (dist2(ex, ey, ez, jx, jy, jz) < THR);
            bool conflict = __any(c0 || c1);
            if (j == t)      k0 = !conflict;
            if (j == t + 64) k1 = !conflict;
        }
        keep_out[b * G_ + t]      = k0 ? 1 : 0;
        keep_out[b * G_ + t + 64] = k1 ? 1 : 0;
    }
}

// ---------------------------------------------------------------------------
// Kernel 2: per-(b,g) ball query (first 128 by index) + top-32 by energy +
// gather/normalize. One 512-thread block per group. (r18-exact: the r20
// XCD-remap + mask fusion regressed and is reverted.)
// ---------------------------------------------------------------------------
__global__ __launch_bounds__(BQ_T) void group_kernel(
    const float4* __restrict__ pts, const int* __restrict__ lengths,
    const float* __restrict__ centers, const int* __restrict__ keep,
    float* __restrict__ groups_out, int* __restrict__ gl) {
    const int bid = blockIdx.x;          // b*128 + g
    const int b = bid >> 7;
    const int t = threadIdx.x;
    const int lane = t & 63;
    const int wv = t >> 6;

    const float cx = centers[bid * 3 + 0];
    const float cy = centers[bid * 3 + 1];
    const float cz = centers[bid * 3 + 2];
    float4* out4 = (float4*)(groups_out + (size_t)bid * GS_ * 4);

    if (!keep[bid]) {
        if (t < GS_) {
            float4 o;
            o.x = __fdiv_rn(__fsub_rn(0.f, cx), 0.1f);
            o.y = __fdiv_rn(__fsub_rn(0.f, cy), 0.1f);
            o.z = __fdiv_rn(__fsub_rn(0.f, cz), 0.1f);
            o.w = 0.f;
            out4[t] = o;
        }
        return;
    }

    __shared__ int   s_widx[BQ_W][UK_];
    __shared__ float s_wen[BQ_W][UK_];
    __shared__ int   s_wcnt[BQ_W];
    __shared__ int   s_list[UK_];
    __shared__ float s_en[UK_];
    __shared__ int   s_ord[GS_];

    const int len = lengths[b];
    const float R2 = (float)(0.1 * 0.1);
    const float4* p = pts + (size_t)b * N_;

    // Per-wave ordered stream compaction over its contiguous eighth.
    {
        const int base0 = wv * (N_ / BQ_W);
        int cnt = 0;
        for (int it = 0; it < (N_ / BQ_W) / 64; it++) {
            int n = base0 + it * 64 + lane;
            float4 q = p[n];
            float d2 = dist2(q.x, q.y, q.z, cx, cy, cz);
            bool pred = (n < len) && (d2 <= R2);
            u64 m = __ballot(pred);
            int prefix = __popcll(m & ((1ull << lane) - 1ull));
            int slot = cnt + prefix;
            if (pred && slot < UK_) { s_widx[wv][slot] = n; s_wen[wv][slot] = q.w; }
            cnt += __popcll(m);
        }
        if (lane == 0) s_wcnt[wv] = (cnt < UK_) ? cnt : UK_;
    }
    __syncthreads();

    int M = 0;
#pragma unroll
    for (int w = 0; w < BQ_W; w++) M += s_wcnt[w];
    if (M > UK_) M = UK_;

    // Ordered merge into unified first-M list.
    if (t < UK_ && t < M) {
        int j = t, w = 0;
        while (w < BQ_W - 1 && j >= s_wcnt[w]) { j -= s_wcnt[w]; w++; }
        s_list[t] = s_widx[w][j];
        s_en[t]   = s_wen[w][j];
    }
    __syncthreads();

    // top-32 by energy, tie -> smaller list position (matches lax.top_k)
    if (wv == 0) {
        float v0 = (lane < M) ? s_en[lane] : -INFINITY;
        float v1 = (lane + 64 < M) ? s_en[lane + 64] : -INFINITY;
        for (int k = 0; k < GS_; k++) {
            float bv; int bs;
            if (v0 >= v1) { bv = v0; bs = lane; }
            else          { bv = v1; bs = lane + 64; }
#pragma unroll
            for (int off = 32; off; off >>= 1) {
                float ov = __shfl_xor(bv, off);
                int   os = __shfl_xor(bs, off);
                bool tk = (ov > bv) || (ov == bv && os < bs);
                bv = tk ? ov : bv; bs = tk ? os : bs;
            }
            if (lane == 0) s_ord[k] = (bv == -INFINITY) ? -1 : bs;
            if (bs == lane)           v0 = -INFINITY;
            else if (bs == lane + 64) v1 = -INFINITY;
        }
    }
    __syncthreads();

    if (t < GS_) {
        int o0 = s_ord[0];
        int first = (o0 >= 0) ? s_list[o0] : -1;
        int ok = s_ord[t];
        int ti = (ok >= 0) ? s_list[ok] : -1;
        int f = (ti == -1) ? first : ti;
        float px = 0.f, py = 0.f, pz = 0.f, pw = 0.f;
        if (f >= 0) { float4 q = p[f]; px = q.x; py = q.y; pz = q.z; pw = q.w; }
        float4 o;
        o.x = __fdiv_rn(__fsub_rn(px, cx), 0.1f);
        o.y = __fdiv_rn(__fsub_rn(py, cy), 0.1f);
        o.z = __fdiv_rn(__fsub_rn(pz, cz), 0.1f);
        o.w = __fdiv_rn(pw, 0.1f);
        out4[t] = o;
    }
    if (t == 0 && M >= GS_) atomicAdd(&gl[b], 1);
}

// ---------------------------------------------------------------------------
// Kernel 3: embedding mask
// ---------------------------------------------------------------------------
__global__ void mask_kernel(const int* __restrict__ gl, float* __restrict__ mask_out) {
    int t = threadIdx.x;                 // 1024 threads
    int b = t >> 7, g = t & 127;
    mask_out[t] = (g < gl[b]) ? 1.0f : 0.0f;
}

extern "C" void kernel_launch(void* const* d_in, const int* in_sizes, int n_in,
                              void* d_out, int out_size, void* d_ws, size_t ws_size,
                              hipStream_t stream) {
    const float4* pts = (const float4*)d_in[0];
    const int* lengths = (const int*)d_in[1];
    float* out = (float*)d_out;
    float* groups = out;                               // B*G*GS*4 = 131072
    float* centers = out + (size_t)B_ * G_ * GS_ * 4;  // +3072
    float* mask = centers + (size_t)B_ * G_ * 3;       // +1024
    u64* slots = (u64*)d_ws;                           // B*G*FPS_BLK u64
    int* keep = (int*)(slots + B_ * G_ * FPS_BLK);     // B*G ints
    int* gl = keep + B_ * G_;                          // B ints

    hipLaunchKernelGGL(fps_cnms_kernel, dim3(B_ * FPS_BLK), dim3(FPS_T), 0, stream,
                       pts, lengths, centers, keep, slots, gl);
    hipLaunchKernelGGL(group_kernel, dim3(B_ * G_), dim3(BQ_T), 0, stream,
                       pts, lengths, centers, keep, groups, gl);
    hipLaunchKernelGGL(mask_kernel, dim3(1), dim3(B_ * G_), 0, stream, gl, mask);
}